// Round 1
// baseline (2084.037 us; speedup 1.0000x reference)
//
#include <hip/hip_runtime.h>

#define T_LEN   131072
#define IN_DIM  256
#define HD      64
#define ENC_OUT 56
#define CTXD    8
#define PD      32
#define NLAY    4
#define CHUNK   256
#define NBLK    (T_LEN / CHUNK)   // 512
#define LSTR    66                // LDS row stride in floats (even -> float2 aligned, 2-way bank max)

__device__ __forceinline__ float gelu_tanh(float t) {
    float u = 0.7978845608028654f * (t + 0.044715f * t * t * t);
    return 0.5f * t * (1.0f + tanhf(u));
}

// ---------------------------------------------------------------- K0: setup
// Discretize: Lbar = exp(Lam*dt), Ldt = Lam*dt, LbarC = Lbar^CHUNK,
// Bbar = ((Lbar-1)/Lam) * B.  Transpose C -> Ct[l][p][c][2], glu w -> w1t/w2t[l][k][c].
// Zero the stats accumulators (must happen every launch: they are atomically accumulated).
__global__ __launch_bounds__(512) void ssm_k0_setup(
    const float* __restrict__ Lre, const float* __restrict__ Lim,
    const float* __restrict__ logstep,
    const float* __restrict__ Bre, const float* __restrict__ Bim,
    const float* __restrict__ Cre, const float* __restrict__ Cim,
    const float* __restrict__ w1, const float* __restrict__ w2,
    float* __restrict__ Lbar, float* __restrict__ Ldt, float* __restrict__ LbarC,
    float* __restrict__ Bbar, float* __restrict__ Ct,
    float* __restrict__ w1t, float* __restrict__ w2t,
    float* __restrict__ stats)
{
    __shared__ float fact[NLAY * PD * 2];
    int tid = threadIdx.x;
    if (tid < NLAY * PD) {
        int l = tid >> 5, p = tid & 31;
        float dt = expf(logstep[l * PD + p]);
        float lr = Lre[l * PD + p], li = Lim[l * PD + p];
        float ldr = lr * dt, ldi = li * dt;
        Ldt[tid * 2] = ldr; Ldt[tid * 2 + 1] = ldi;
        float e = expf(ldr);
        float sn, cs; sincosf(ldi, &sn, &cs);
        float lbr = e * cs, lbi = e * sn;
        Lbar[tid * 2] = lbr; Lbar[tid * 2 + 1] = lbi;
        float eC = expf(ldr * (float)CHUNK);
        float snC, csC; sincosf(ldi * (float)CHUNK, &snC, &csC);
        LbarC[tid * 2] = eC * csC; LbarC[tid * 2 + 1] = eC * snC;
        float den = lr * lr + li * li;
        float nr = lbr - 1.0f, ni = lbi;
        fact[tid * 2]     = (nr * lr + ni * li) / den;
        fact[tid * 2 + 1] = (ni * lr - nr * li) / den;
    }
    if (tid < NLAY * 128) stats[tid] = 0.0f;
    __syncthreads();
    for (int idx = tid; idx < NLAY * PD * HD; idx += 512) {
        int lp = idx >> 6; int c = idx & 63;
        float fr = fact[lp * 2], fi = fact[lp * 2 + 1];
        float br = Bre[idx], bi = Bim[idx];           // B is [l][p][h] already
        Bbar[idx * 2]     = fr * br - fi * bi;
        Bbar[idx * 2 + 1] = fr * bi + fi * br;
        int l = lp >> 5, p = lp & 31;
        Ct[idx * 2]     = Cre[(l * HD + c) * PD + p]; // C is [l][h][p]
        Ct[idx * 2 + 1] = Cim[(l * HD + c) * PD + p];
    }
    for (int idx = tid; idx < NLAY * HD * HD; idx += 512) {
        int l = idx >> 12; int k = (idx >> 6) & 63; int c = idx & 63;
        w1t[idx] = w1[(l * HD + c) * HD + k];
        w2t[idx] = w2[(l * HD + c) * HD + k];
    }
}

// ---------------------------------------------------------------- K1: encoder
// h = x @ enc_w[g].T + enc_b[g] ; h[:,56:64] = ctx ; accumulate layer-0 stats.
// 512 blocks x 4 tiles of 64 rows.  x tile staged in LDS (stride 260: b128-balanced),
// weights read with block-uniform addresses -> s_load (scalar cache).
__global__ __launch_bounds__(256) void ssm_k1_encoder(
    const float* __restrict__ x, const int* __restrict__ gptr,
    const float* __restrict__ enc_w, const float* __restrict__ enc_b,
    const float* __restrict__ ctx_emb,
    float* __restrict__ h, float* __restrict__ stats)
{
    __shared__ float xl[64 * 260];
    int tid = threadIdx.x;
    int g = __builtin_amdgcn_readfirstlane(gptr[0]);
    int q = __builtin_amdgcn_readfirstlane(tid >> 6);   // wave id = out-quarter
    int r = tid & 63;                                   // row within tile
    float st1[14], st2[14];
#pragma unroll
    for (int o = 0; o < 14; ++o) { st1[o] = 0.0f; st2[o] = 0.0f; }
    float ctxv[8];
#pragma unroll
    for (int j = 0; j < 8; ++j) ctxv[j] = ctx_emb[g * CTXD + j];

    for (int it = 0; it < 4; ++it) {
        int tile = blockIdx.x * 4 + it;
        int r0 = tile * 64;
        __syncthreads();          // protect xl from previous-iteration readers
        for (int i = 0; i < 16; ++i) {
            int f4 = i * 256 + tid;
            int row = f4 >> 6, c4 = f4 & 63;
            *(float4*)&xl[row * 260 + c4 * 4] =
                *(const float4*)&x[(size_t)(r0 + row) * IN_DIM + c4 * 4];
        }
        __syncthreads();
        float acc[14];
#pragma unroll
        for (int o = 0; o < 14; ++o) acc[o] = enc_b[g * ENC_OUT + q * 14 + o];
        for (int k4 = 0; k4 < 64; ++k4) {
            float4 xv = *(const float4*)&xl[r * 260 + k4 * 4];
#pragma unroll
            for (int o = 0; o < 14; ++o) {
                const float4 wv = *(const float4*)
                    &enc_w[((size_t)(g * ENC_OUT + q * 14 + o)) * IN_DIM + k4 * 4];
                acc[o] += xv.x * wv.x + xv.y * wv.y + xv.z * wv.z + xv.w * wv.w;
            }
        }
#pragma unroll
        for (int o = 0; o < 14; ++o) { st1[o] += acc[o]; st2[o] += acc[o] * acc[o]; }
        __syncthreads();          // all xl reads done before aliasing as hb
        float* hb = xl;           // alias: [64][66]
#pragma unroll
        for (int o = 0; o < 14; ++o) hb[r * LSTR + q * 14 + o] = acc[o];
        if (q == 3) {
#pragma unroll
            for (int j = 0; j < 8; ++j) hb[r * LSTR + ENC_OUT + j] = ctxv[j];
        }
        __syncthreads();
        for (int i = 0; i < 8; ++i) {
            int f2 = i * 256 + tid;
            int row = f2 >> 5, c2 = f2 & 31;
            *(float2*)&h[(size_t)(r0 + row) * HD + c2 * 2] =
                *(float2*)&hb[row * LSTR + c2 * 2];
        }
    }
    // layer-0 statistics (channels 0..55 per-wave; ctx channels analytic)
#pragma unroll
    for (int o = 0; o < 14; ++o) {
        float v1 = st1[o], v2 = st2[o];
#pragma unroll
        for (int m = 1; m < 64; m <<= 1) { v1 += __shfl_xor(v1, m); v2 += __shfl_xor(v2, m); }
        if (r == 0) {
            atomicAdd(&stats[q * 14 + o], v1);
            atomicAdd(&stats[64 + q * 14 + o], v2);
        }
    }
    if (tid == 192) {
#pragma unroll
        for (int j = 0; j < 8; ++j) {
            float v = ctxv[j];
            atomicAdd(&stats[ENC_OUT + j], 256.0f * v);
            atomicAdd(&stats[64 + ENC_OUT + j], 256.0f * v * v);
        }
    }
}

// ---------------------------------------------------------------- K2: hn -> Bu -> local scan
// One block per 256-row chunk.  hn computed on the fly (h*a+b with folded norm),
// Bu written to LDS, wave0 does the sequential in-chunk scan, writes xs + carry.
__global__ __launch_bounds__(256) void ssm_k2_bu_scan(
    const float* __restrict__ h, const float* __restrict__ stats,
    const float* __restrict__ nscale, const float* __restrict__ nbias,
    const float* __restrict__ Bbar, const float* __restrict__ Lbar,
    float* __restrict__ xs, float* __restrict__ carry, int l)
{
    __shared__ float buf[CHUNK * LSTR];
    __shared__ float sa[HD], sb[HD];
    int tid = threadIdx.x;
    int r0 = blockIdx.x * CHUNK;
    for (int i = 0; i < 32; ++i) {
        int f2 = i * 256 + tid;
        int row = f2 >> 5, c2 = f2 & 31;
        *(float2*)&buf[row * LSTR + c2 * 2] =
            *(const float2*)&h[(size_t)(r0 + row) * HD + c2 * 2];
    }
    if (tid < HD) {
        float s1 = stats[l * 128 + tid], s2 = stats[l * 128 + 64 + tid];
        float mu = s1 * (1.0f / T_LEN);
        float var = fmaxf(s2 * (1.0f / T_LEN) - mu * mu, 0.0f);
        float rstd = rsqrtf(var + 1e-5f);
        float sc = nscale[l * HD + tid] * rstd;
        sa[tid] = sc;
        sb[tid] = nbias[l * HD + tid] - mu * sc;
    }
    __syncthreads();
    float hn[HD];
#pragma unroll
    for (int c = 0; c < HD; ++c) hn[c] = buf[tid * LSTR + c] * sa[c] + sb[c];
    __syncthreads();
    for (int p = 0; p < PD; ++p) {
        const float* bb = &Bbar[((size_t)(l * PD + p)) * HD * 2];
        float br = 0.0f, bi = 0.0f;
#pragma unroll
        for (int c = 0; c < HD; ++c) { br += hn[c] * bb[2 * c]; bi += hn[c] * bb[2 * c + 1]; }
        *(float2*)&buf[tid * LSTR + 2 * p] = make_float2(br, bi);
    }
    __syncthreads();
    if (tid < PD) {
        float2 L = *(const float2*)&Lbar[(l * PD + tid) * 2];
        float xr = 0.0f, xi = 0.0f;
        for (int t = 0; t < CHUNK; ++t) {
            float2 b = *(float2*)&buf[t * LSTR + 2 * tid];
            float nr = L.x * xr - L.y * xi + b.x;
            float ni = L.x * xi + L.y * xr + b.y;
            xr = nr; xi = ni;
            *(float2*)&xs[(size_t)(r0 + t) * HD + 2 * tid] = make_float2(xr, xi);
        }
        *(float2*)&carry[blockIdx.x * HD + 2 * tid] = make_float2(xr, xi);
    }
}

// ---------------------------------------------------------------- K3: cross-chunk carry scan
__global__ void ssm_k3_carry(const float* __restrict__ carry,
                             const float* __restrict__ LbarC,
                             float* __restrict__ pc, int l)
{
    int p = threadIdx.x;
    if (p >= PD) return;
    float2 LC = *(const float2*)&LbarC[(l * PD + p) * 2];
    float xr = 0.0f, xi = 0.0f;
    for (int b = 0; b < NBLK; ++b) {
        *(float2*)&pc[b * HD + 2 * p] = make_float2(xr, xi);   // exclusive prefix
        float2 cv = *(const float2*)&carry[b * HD + 2 * p];
        float nr = LC.x * xr - LC.y * xi + cv.x;
        float ni = LC.x * xi + LC.y * xr + cv.y;
        xr = nr; xi = ni;
    }
}

// ---------------------------------------------------------------- K4: fixup + C-proj + gelu + GLU + residual (+ stats / decoder)
template <bool LAST>
__global__ __launch_bounds__(256) void ssm_k4_out(
    const float* __restrict__ h, const float* __restrict__ xs,
    const float* __restrict__ pc, const float* __restrict__ stats,
    const float* __restrict__ nscale, const float* __restrict__ nbias,
    const float* __restrict__ Ldt, const float* __restrict__ Ct,
    const float* __restrict__ Dv,
    const float* __restrict__ w1t, const float* __restrict__ b1,
    const float* __restrict__ w2t, const float* __restrict__ b2,
    float* __restrict__ hout_g, float* __restrict__ stats_next,
    const float* __restrict__ dec_w, const float* __restrict__ dec_b,
    float* __restrict__ outp, int l)
{
    __shared__ float buf[CHUNK * LSTR];
    __shared__ float sa[HD], sb[HD];
    __shared__ float sp[4 * 128];
    int tid = threadIdx.x;
    int r0 = blockIdx.x * CHUNK;
    // stage xs tile
    for (int i = 0; i < 32; ++i) {
        int f2 = i * 256 + tid;
        int row = f2 >> 5, c2 = f2 & 31;
        *(float2*)&buf[row * LSTR + c2 * 2] =
            *(const float2*)&xs[(size_t)(r0 + row) * HD + c2 * 2];
    }
    if (tid < HD) {
        float s1 = stats[l * 128 + tid], s2 = stats[l * 128 + 64 + tid];
        float mu = s1 * (1.0f / T_LEN);
        float var = fmaxf(s2 * (1.0f / T_LEN) - mu * mu, 0.0f);
        float rstd = rsqrtf(var + 1e-5f);
        float sc = nscale[l * HD + tid] * rstd;
        sa[tid] = sc;
        sb[tid] = nbias[l * HD + tid] - mu * sc;
    }
    __syncthreads();
    float y[HD];
#pragma unroll
    for (int c = 0; c < HD; ++c) y[c] = 0.0f;
    float tt = (float)(tid + 1);
    for (int p = 0; p < PD; ++p) {
        float2 v   = *(float2*)&buf[tid * LSTR + 2 * p];
        float2 pcv = *(const float2*)&pc[blockIdx.x * HD + 2 * p];     // uniform
        float2 ld  = *(const float2*)&Ldt[(l * PD + p) * 2];           // uniform
        float e = expf(ld.x * tt);
        float sn, cs; sincosf(ld.y * tt, &sn, &cs);
        float pr = e * cs, pi = e * sn;
        float xr = v.x + pr * pcv.x - pi * pcv.y;
        float xi = v.y + pr * pcv.y + pi * pcv.x;
        const float* ct = &Ct[((size_t)(l * PD + p)) * HD * 2];
#pragma unroll
        for (int c = 0; c < HD; ++c) y[c] += xr * ct[2 * c] - xi * ct[2 * c + 1];
    }
    __syncthreads();
    // stage h tile (old h: needed for hn and residual)
    for (int i = 0; i < 32; ++i) {
        int f2 = i * 256 + tid;
        int row = f2 >> 5, c2 = f2 & 31;
        *(float2*)&buf[row * LSTR + c2 * 2] =
            *(const float2*)&h[(size_t)(r0 + row) * HD + c2 * 2];
    }
    __syncthreads();
    float hrow[HD];
#pragma unroll
    for (int c = 0; c < HD; ++c) {
        float hv = buf[tid * LSTR + c];
        float hnv = hv * sa[c] + sb[c];
        float t = 2.0f * y[c] + hnv * Dv[l * HD + c];
        hrow[c] = hv;
        buf[tid * LSTR + c] = gelu_tanh(t);     // in-place per-row: safe
    }
    float uacc[HD], sacc[HD];
#pragma unroll
    for (int c = 0; c < HD; ++c) { uacc[c] = b1[l * HD + c]; sacc[c] = b2[l * HD + c]; }
    for (int k = 0; k < HD; ++k) {
        float yk = buf[tid * LSTR + k];
        const float* w1p = &w1t[(size_t)(l * HD + k) * HD];
        const float* w2p = &w2t[(size_t)(l * HD + k) * HD];
#pragma unroll
        for (int c = 0; c < HD; ++c) { uacc[c] += yk * w1p[c]; sacc[c] += yk * w2p[c]; }
    }
    float o0 = 0.0f, o1 = 0.0f;
    int wid = tid >> 6, lane = tid & 63;
#pragma unroll
    for (int c = 0; c < HD; ++c) {
        float sg = 1.0f / (1.0f + expf(-sacc[c]));
        float ho = hrow[c] + uacc[c] * sg;
        if (LAST) {
            o0 += ho * dec_w[c];
            o1 += ho * dec_w[HD + c];
        } else {
            buf[tid * LSTR + c] = ho;
            float v1 = ho, v2 = ho * ho;
#pragma unroll
            for (int m = 1; m < 64; m <<= 1) { v1 += __shfl_xor(v1, m); v2 += __shfl_xor(v2, m); }
            if (lane == 0) { sp[wid * 128 + c] = v1; sp[wid * 128 + 64 + c] = v2; }
        }
    }
    if (LAST) {
        *(float2*)&outp[(size_t)(r0 + tid) * 2] = make_float2(o0 + dec_b[0], o1 + dec_b[1]);
    } else {
        __syncthreads();
        for (int i = 0; i < 32; ++i) {
            int f2 = i * 256 + tid;
            int row = f2 >> 5, c2 = f2 & 31;
            *(float2*)&hout_g[(size_t)(r0 + row) * HD + c2 * 2] =
                *(float2*)&buf[row * LSTR + c2 * 2];
        }
        if (tid < 128) {
            float v = sp[tid] + sp[128 + tid] + sp[256 + tid] + sp[384 + tid];
            atomicAdd(&stats_next[tid], v);
        }
    }
}

// ---------------------------------------------------------------- launch
extern "C" void kernel_launch(void* const* d_in, const int* in_sizes, int n_in,
                              void* d_out, int out_size, void* d_ws, size_t ws_size,
                              hipStream_t stream)
{
    (void)in_sizes; (void)n_in; (void)out_size; (void)ws_size;
    const float* x     = (const float*)d_in[0];
    const int*   gidx  = (const int*)d_in[1];
    const float* enc_w = (const float*)d_in[2];
    const float* enc_b = (const float*)d_in[3];
    const float* ctx   = (const float*)d_in[4];
    const float* Lre   = (const float*)d_in[5];
    const float* Lim   = (const float*)d_in[6];
    const float* Bre   = (const float*)d_in[7];
    const float* Bim   = (const float*)d_in[8];
    const float* Cre   = (const float*)d_in[9];
    const float* Cim   = (const float*)d_in[10];
    const float* Dv    = (const float*)d_in[11];
    const float* lstep = (const float*)d_in[12];
    const float* nsc   = (const float*)d_in[13];
    const float* nbi   = (const float*)d_in[14];
    const float* w1    = (const float*)d_in[15];
    const float* b1    = (const float*)d_in[16];
    const float* w2    = (const float*)d_in[17];
    const float* b2    = (const float*)d_in[18];
    const float* dw    = (const float*)d_in[19];
    const float* db    = (const float*)d_in[20];
    float* out = (float*)d_out;

    float* ws = (float*)d_ws;
    float* h     = ws;  ws += (size_t)T_LEN * HD;
    float* xs    = ws;  ws += (size_t)T_LEN * HD;
    float* carry = ws;  ws += NBLK * HD;
    float* pc    = ws;  ws += NBLK * HD;
    float* stats = ws;  ws += NLAY * 128;
    float* Lbar  = ws;  ws += NLAY * PD * 2;
    float* Ldt   = ws;  ws += NLAY * PD * 2;
    float* LbarC = ws;  ws += NLAY * PD * 2;
    float* Bbar  = ws;  ws += NLAY * PD * HD * 2;
    float* Ct    = ws;  ws += NLAY * PD * HD * 2;
    float* w1t   = ws;  ws += NLAY * HD * HD;
    float* w2t   = ws;  ws += NLAY * HD * HD;

    ssm_k0_setup<<<1, 512, 0, stream>>>(Lre, Lim, lstep, Bre, Bim, Cre, Cim, w1, w2,
                                        Lbar, Ldt, LbarC, Bbar, Ct, w1t, w2t, stats);
    ssm_k1_encoder<<<512, 256, 0, stream>>>(x, gidx, enc_w, enc_b, ctx, h, stats);
    for (int l = 0; l < NLAY; ++l) {
        ssm_k2_bu_scan<<<NBLK, 256, 0, stream>>>(h, stats, nsc, nbi, Bbar, Lbar, xs, carry, l);
        ssm_k3_carry<<<1, 64, 0, stream>>>(carry, LbarC, pc, l);
        if (l < NLAY - 1) {
            ssm_k4_out<false><<<NBLK, 256, 0, stream>>>(
                h, xs, pc, stats, nsc, nbi, Ldt, Ct, Dv, w1t, b1, w2t, b2,
                h, stats + (l + 1) * 128, dw, db, out, l);
        } else {
            ssm_k4_out<true><<<NBLK, 256, 0, stream>>>(
                h, xs, pc, stats, nsc, nbi, Ldt, Ct, Dv, w1t, b1, w2t, b2,
                h, stats, dw, db, out, l);
        }
    }
}

// Round 2
// 609.818 us; speedup vs baseline: 3.4175x; 3.4175x over previous
//
#include <hip/hip_runtime.h>

#define T_LEN   131072
#define IN_DIM  256
#define HD      64
#define PD      32
#define NLAY    4
#define CHUNK   128
#define NBLK    (T_LEN / CHUNK)   // 1024

// ---------------------------------------------------------------- K0: setup
// Discretize Lambda, build transposed weight layouts, zero stats.
__global__ __launch_bounds__(512) void ssm_k0_setup(
    const float* __restrict__ Lre, const float* __restrict__ Lim,
    const float* __restrict__ logstep,
    const float* __restrict__ Bre, const float* __restrict__ Bim,
    const float* __restrict__ Cre, const float* __restrict__ Cim,
    const float* __restrict__ w1, const float* __restrict__ w2,
    const float* __restrict__ enc_w, const int* __restrict__ gptr,
    float* __restrict__ Lbar, float* __restrict__ Ldt,
    float* __restrict__ Bbar_t, float* __restrict__ Ct,
    float* __restrict__ w1t, float* __restrict__ w2t,
    float* __restrict__ wenc, float* __restrict__ stats)
{
    __shared__ float fact[NLAY * PD * 2];
    int tid = threadIdx.x;
    if (tid < NLAY * PD) {
        int l = tid >> 5, p = tid & 31;
        float dt = expf(logstep[l * PD + p]);
        float lr = Lre[l * PD + p], li = Lim[l * PD + p];
        float ldr = lr * dt, ldi = li * dt;
        Ldt[tid * 2] = ldr; Ldt[tid * 2 + 1] = ldi;
        float e = expf(ldr);
        float sn, cs; sincosf(ldi, &sn, &cs);
        float lbr = e * cs, lbi = e * sn;
        Lbar[tid * 2] = lbr; Lbar[tid * 2 + 1] = lbi;
        float den = lr * lr + li * li;
        float nr = lbr - 1.0f, ni = lbi;
        fact[tid * 2]     = (nr * lr + ni * li) / den;
        fact[tid * 2 + 1] = (ni * lr - nr * li) / den;
    }
    if (tid < NLAY * 128) stats[tid] = 0.0f;
    __syncthreads();
    // Bbar_t[l][c][2p] ; Ct planes [l][p][re:0..63 | im:64..127]
    for (int idx = tid; idx < NLAY * PD * HD; idx += 512) {
        int lp = idx >> 6; int c = idx & 63;
        int l = lp >> 5, p = lp & 31;
        float fr = fact[lp * 2], fi = fact[lp * 2 + 1];
        float br = Bre[idx], bi = Bim[idx];                    // B is [l][p][h]
        Bbar_t[((size_t)(l * HD + c)) * HD + 2 * p]     = fr * br - fi * bi;
        Bbar_t[((size_t)(l * HD + c)) * HD + 2 * p + 1] = fr * bi + fi * br;
        Ct[((size_t)(l * PD + p)) * 128 + c]      = Cre[(l * HD + c) * PD + p];
        Ct[((size_t)(l * PD + p)) * 128 + 64 + c] = Cim[(l * HD + c) * PD + p];
    }
    for (int idx = tid; idx < NLAY * HD * HD; idx += 512) {
        int l = idx >> 12; int k = (idx >> 6) & 63; int c = idx & 63;
        w1t[idx] = w1[(l * HD + c) * HD + k];
        w2t[idx] = w2[(l * HD + c) * HD + k];
    }
    int g = gptr[0];
    for (int idx = tid; idx < IN_DIM * HD; idx += 512) {
        int k = idx >> 6, ch = idx & 63;
        wenc[idx] = (ch < 56) ? enc_w[((size_t)(g * 56 + ch)) * IN_DIM + k] : 0.0f;
    }
}

// ---------------------------------------------------------------- K1: encoder
// grid 1024 x 256 threads. 128 rows/block; thread = (row=tid>>2 [+64], cg=tid&3).
__global__ __launch_bounds__(256, 4) void ssm_k1_encoder(
    const float* __restrict__ x, const int* __restrict__ gptr,
    const float* __restrict__ wenc, const float* __restrict__ enc_b,
    const float* __restrict__ ctx_emb,
    float* __restrict__ h, float* __restrict__ stats)
{
    __shared__ __attribute__((aligned(16))) float xl[128 * 68];
    __shared__ __attribute__((aligned(16))) float wl[64 * 68];
    __shared__ float sp[4 * 128];
    int tid = threadIdx.x;
    int row = tid >> 2, cg = tid & 3;
    int lane = tid & 63, wid = tid >> 6;
    int g = gptr[0];
    size_t r0 = (size_t)blockIdx.x * 128;

    float ctxv[8];
#pragma unroll
    for (int j = 0; j < 8; ++j) ctxv[j] = ctx_emb[g * 8 + j];

    float acc[2][16];
#pragma unroll
    for (int rb = 0; rb < 2; ++rb)
#pragma unroll
        for (int i = 0; i < 16; ++i) {
            int ch = cg * 16 + i;
            acc[rb][i] = (ch < 56) ? enc_b[g * 56 + ch] : 0.0f;
        }

    for (int kt = 0; kt < 4; ++kt) {
        __syncthreads();
#pragma unroll
        for (int it = 0; it < 4; ++it) {
            int idx = it * 256 + tid; int kk = idx >> 4, c4 = idx & 15;
            *(float4*)&wl[kk * 68 + c4 * 4] =
                *(const float4*)&wenc[(kt * 64 + kk) * HD + c4 * 4];
        }
#pragma unroll
        for (int it = 0; it < 8; ++it) {
            int idx = it * 256 + tid; int rr = idx >> 4, c4 = idx & 15;
            *(float4*)&xl[rr * 68 + c4 * 4] =
                *(const float4*)&x[(r0 + rr) * IN_DIM + kt * 64 + c4 * 4];
        }
        __syncthreads();
        for (int k = 0; k < 64; ++k) {
            float4 w0 = *(float4*)&wl[k * 68 + cg * 16];
            float4 w1v = *(float4*)&wl[k * 68 + cg * 16 + 4];
            float4 w2v = *(float4*)&wl[k * 68 + cg * 16 + 8];
            float4 w3v = *(float4*)&wl[k * 68 + cg * 16 + 12];
#pragma unroll
            for (int rb = 0; rb < 2; ++rb) {
                float xv = xl[(rb * 64 + row) * 68 + k];
                acc[rb][0]  += xv * w0.x;  acc[rb][1]  += xv * w0.y;
                acc[rb][2]  += xv * w0.z;  acc[rb][3]  += xv * w0.w;
                acc[rb][4]  += xv * w1v.x; acc[rb][5]  += xv * w1v.y;
                acc[rb][6]  += xv * w1v.z; acc[rb][7]  += xv * w1v.w;
                acc[rb][8]  += xv * w2v.x; acc[rb][9]  += xv * w2v.y;
                acc[rb][10] += xv * w2v.z; acc[rb][11] += xv * w2v.w;
                acc[rb][12] += xv * w3v.x; acc[rb][13] += xv * w3v.y;
                acc[rb][14] += xv * w3v.z; acc[rb][15] += xv * w3v.w;
            }
        }
    }
    // ctx channels override (56..63)
    if (cg == 3) {
#pragma unroll
        for (int rb = 0; rb < 2; ++rb)
#pragma unroll
            for (int i = 8; i < 16; ++i) acc[rb][i] = ctxv[i - 8];
    }
    // write h (coalesced float4)
#pragma unroll
    for (int rb = 0; rb < 2; ++rb)
#pragma unroll
        for (int j4 = 0; j4 < 4; ++j4) {
            float4 v = make_float4(acc[rb][j4 * 4], acc[rb][j4 * 4 + 1],
                                   acc[rb][j4 * 4 + 2], acc[rb][j4 * 4 + 3]);
            *(float4*)&h[(r0 + rb * 64 + row) * HD + cg * 16 + j4 * 4] = v;
        }
    // layer-0 stats
#pragma unroll
    for (int i = 0; i < 16; ++i) {
        float v1 = acc[0][i] + acc[1][i];
        float v2 = acc[0][i] * acc[0][i] + acc[1][i] * acc[1][i];
#pragma unroll
        for (int m = 4; m < 64; m <<= 1) { v1 += __shfl_xor(v1, m, 64); v2 += __shfl_xor(v2, m, 64); }
        if ((lane >> 2) == 0) {
            sp[wid * 128 + cg * 16 + i] = v1;
            sp[wid * 128 + 64 + cg * 16 + i] = v2;
        }
    }
    __syncthreads();
    if (tid < 128) {
        float v = sp[tid] + sp[128 + tid] + sp[256 + tid] + sp[384 + tid];
        atomicAdd(&stats[tid], v);
    }
}

// ---------------------------------------------------------------- K2: hn -> Bu -> local scan
// grid 1024 x 512 threads; 128 rows/block; thread = (row=tid>>2, cg=tid&3).
__global__ __launch_bounds__(512, 4) void ssm_k2_bu_scan(
    const float* __restrict__ h, const float* __restrict__ stats,
    const float* __restrict__ nscale, const float* __restrict__ nbias,
    const float* __restrict__ Bbar_t, const float* __restrict__ Lbar,
    float* __restrict__ xs, float* __restrict__ carry, int l)
{
    __shared__ __attribute__((aligned(16))) float bb[64 * 64];   // [c][2p]
    __shared__ __attribute__((aligned(16))) float bu[128 * 68];  // [t][2p], stride 68
    __shared__ float sa[HD], sb[HD];
    int tid = threadIdx.x;
    int row = tid >> 2, cg = tid & 3;
    int lane = tid & 63;
    int wbase = lane & ~3;
    size_t r0 = (size_t)blockIdx.x * CHUNK;

#pragma unroll
    for (int it = 0; it < 2; ++it) {
        int idx = it * 512 + tid;
        *(float4*)&bb[idx * 4] = *(const float4*)&Bbar_t[(size_t)l * 4096 + idx * 4];
    }
    if (tid < HD) {
        float s1 = stats[l * 128 + tid], s2 = stats[l * 128 + 64 + tid];
        float mu = s1 * (1.0f / T_LEN);
        float var = fmaxf(s2 * (1.0f / T_LEN) - mu * mu, 0.0f);
        float sc = nscale[l * HD + tid] * rsqrtf(var + 1e-5f);
        sa[tid] = sc;
        sb[tid] = nbias[l * HD + tid] - mu * sc;
    }
    __syncthreads();

    // hn for my 16 channels
    float hn[16];
#pragma unroll
    for (int j4 = 0; j4 < 4; ++j4) {
        float4 hv = *(const float4*)&h[(r0 + row) * HD + cg * 16 + j4 * 4];
        int c = cg * 16 + j4 * 4;
        hn[j4 * 4]     = hv.x * sa[c]     + sb[c];
        hn[j4 * 4 + 1] = hv.y * sa[c + 1] + sb[c + 1];
        hn[j4 * 4 + 2] = hv.z * sa[c + 2] + sb[c + 2];
        hn[j4 * 4 + 3] = hv.w * sa[c + 3] + sb[c + 3];
    }
    // Bu for my 8 complex p's (interleaved re,im = 16 floats)
    float bacc[16];
#pragma unroll
    for (int j = 0; j < 16; ++j) bacc[j] = 0.0f;
    for (int cgrp = 0; cgrp < 4; ++cgrp) {
        int src = wbase | cgrp;
#pragma unroll
        for (int i = 0; i < 16; ++i) {
            float hnc = __shfl(hn[i], src, 64);
            const float* bp = &bb[(cgrp * 16 + i) * 64 + cg * 16];
            float4 b0 = *(float4*)&bp[0];
            float4 b1 = *(float4*)&bp[4];
            float4 b2 = *(float4*)&bp[8];
            float4 b3 = *(float4*)&bp[12];
            bacc[0]  += hnc * b0.x;  bacc[1]  += hnc * b0.y;
            bacc[2]  += hnc * b0.z;  bacc[3]  += hnc * b0.w;
            bacc[4]  += hnc * b1.x;  bacc[5]  += hnc * b1.y;
            bacc[6]  += hnc * b1.z;  bacc[7]  += hnc * b1.w;
            bacc[8]  += hnc * b2.x;  bacc[9]  += hnc * b2.y;
            bacc[10] += hnc * b2.z;  bacc[11] += hnc * b2.w;
            bacc[12] += hnc * b3.x;  bacc[13] += hnc * b3.y;
            bacc[14] += hnc * b3.z;  bacc[15] += hnc * b3.w;
        }
    }
#pragma unroll
    for (int j4 = 0; j4 < 4; ++j4)
        *(float4*)&bu[row * 68 + cg * 16 + j4 * 4] =
            make_float4(bacc[j4 * 4], bacc[j4 * 4 + 1], bacc[j4 * 4 + 2], bacc[j4 * 4 + 3]);
    __syncthreads();

    // in-chunk scan: wave 0, lane = 2p+ri
    if (tid < 64) {
        int p = lane >> 1;
        float Lr = Lbar[(l * PD + p) * 2];
        float Lj = Lbar[(l * PD + p) * 2 + 1];
        float csn = (lane & 1) ? Lj : -Lj;
        float xv = 0.0f;
        for (int t = 0; t < CHUNK; ++t) {
            float b = bu[t * 68 + lane];
            float xo = __shfl_xor(xv, 1, 64);
            xv = Lr * xv + csn * xo + b;
            bu[t * 68 + lane] = xv;
        }
        carry[(size_t)blockIdx.x * 64 + lane] = xv;
    }
    __syncthreads();
#pragma unroll
    for (int j4 = 0; j4 < 4; ++j4)
        *(float4*)&xs[(r0 + row) * HD + cg * 16 + j4 * 4] =
            *(float4*)&bu[row * 68 + cg * 16 + j4 * 4];
}

// ---------------------------------------------------------------- K3: cross-chunk carry scan (wave-parallel)
// grid 32 (one block per p), 64 lanes; lane owns 16 consecutive chunks.
__global__ __launch_bounds__(64) void ssm_k3_carry(
    const float* __restrict__ carry, const float* __restrict__ Ldt,
    float* __restrict__ pc, int l)
{
    int p = blockIdx.x;
    int lane = threadIdx.x;
    float ldr = Ldt[(l * PD + p) * 2], ldi = Ldt[(l * PD + p) * 2 + 1];
    float er = __expf(ldr * (float)CHUNK);
    float an = ldi * (float)CHUNK;
    float lcr = er * __cosf(an), lci = er * __sinf(an);   // L^CHUNK
    float cr[16], ci[16];
#pragma unroll
    for (int j = 0; j < 16; ++j) {
        cr[j] = carry[(size_t)(lane * 16 + j) * 64 + 2 * p];
        ci[j] = carry[(size_t)(lane * 16 + j) * 64 + 2 * p + 1];
    }
    float ur = 0.0f, ui = 0.0f;
#pragma unroll
    for (int j = 0; j < 16; ++j) {
        float nr = lcr * ur - lci * ui + cr[j];
        float ni = lcr * ui + lci * ur + ci[j];
        ur = nr; ui = ni;
    }
    // m = LC^16
    float mr = lcr, mi = lci;
#pragma unroll
    for (int s = 0; s < 4; ++s) { float t = mr * mr - mi * mi; mi = 2.0f * mr * mi; mr = t; }
    // Hillis-Steele inclusive scan across lanes
#pragma unroll
    for (int d = 1; d < 64; d <<= 1) {
        float tr = __shfl_up(ur, d, 64);
        float ti = __shfl_up(ui, d, 64);
        if (lane >= d) { ur = mr * tr - mi * ti + ur; ui = mr * ti + mi * tr + ui; }
        float t = mr * mr - mi * mi; mi = 2.0f * mr * mi; mr = t;
    }
    float pr = __shfl_up(ur, 1, 64), pi = __shfl_up(ui, 1, 64);
    float xr = (lane == 0) ? 0.0f : pr;
    float xi = (lane == 0) ? 0.0f : pi;
#pragma unroll
    for (int j = 0; j < 16; ++j) {
        pc[(size_t)(lane * 16 + j) * 64 + 2 * p]     = xr;
        pc[(size_t)(lane * 16 + j) * 64 + 2 * p + 1] = xi;
        float nr = lcr * xr - lci * xi + cr[j];
        float ni = lcr * xi + lci * xr + ci[j];
        xr = nr; xi = ni;
    }
}

// ---------------------------------------------------------------- K4: fixup + C-proj + gelu + GLU + residual (+stats / decoder)
template <bool LAST>
__global__ __launch_bounds__(512, 4) void ssm_k4_out(
    const float* __restrict__ h, const float* __restrict__ xs,
    const float* __restrict__ pc, const float* __restrict__ stats,
    const float* __restrict__ nscale, const float* __restrict__ nbias,
    const float* __restrict__ Ldt, const float* __restrict__ Ct,
    const float* __restrict__ Dv,
    const float* __restrict__ w1t, const float* __restrict__ b1,
    const float* __restrict__ w2t, const float* __restrict__ b2,
    float* __restrict__ hout, float* __restrict__ stats_next,
    const float* __restrict__ dec_w, const float* __restrict__ dec_b,
    float* __restrict__ outp, int l)
{
    __shared__ __attribute__((aligned(16))) float ct[32 * 128];  // [p][re0..63|im64..127]
    __shared__ __attribute__((aligned(16))) float wl1[64 * 64];
    __shared__ __attribute__((aligned(16))) float wl2[64 * 64];
    __shared__ float sa[HD], sb[HD];
    __shared__ float sp[8 * 128];
    int tid = threadIdx.x;
    int row = tid >> 2, cg = tid & 3;
    int lane = tid & 63, wid = tid >> 6;
    int wbase = lane & ~3;
    size_t r0 = (size_t)blockIdx.x * CHUNK;

#pragma unroll
    for (int it = 0; it < 2; ++it) {
        int idx = it * 512 + tid;
        *(float4*)&ct[idx * 4]  = *(const float4*)&Ct[(size_t)l * 4096 + idx * 4];
        *(float4*)&wl1[idx * 4] = *(const float4*)&w1t[(size_t)l * 4096 + idx * 4];
        *(float4*)&wl2[idx * 4] = *(const float4*)&w2t[(size_t)l * 4096 + idx * 4];
    }
    if (tid < HD) {
        float s1 = stats[l * 128 + tid], s2 = stats[l * 128 + 64 + tid];
        float mu = s1 * (1.0f / T_LEN);
        float var = fmaxf(s2 * (1.0f / T_LEN) - mu * mu, 0.0f);
        float sc = nscale[l * HD + tid] * rsqrtf(var + 1e-5f);
        sa[tid] = sc;
        sb[tid] = nbias[l * HD + tid] - mu * sc;
    }
    __syncthreads();

    // load xs (my 8 complex) + fixup with pc * Lbar^(t+1)
    float xf[16];
#pragma unroll
    for (int j4 = 0; j4 < 4; ++j4)
        *(float4*)&xf[j4 * 4] = *(const float4*)&xs[(r0 + row) * HD + cg * 16 + j4 * 4];
    {
        float ldv[16], pcv[16];
#pragma unroll
        for (int j4 = 0; j4 < 4; ++j4) {
            *(float4*)&ldv[j4 * 4] = *(const float4*)&Ldt[(l * PD + cg * 8) * 2 + j4 * 4];
            *(float4*)&pcv[j4 * 4] = *(const float4*)&pc[(size_t)blockIdx.x * 64 + cg * 16 + j4 * 4];
        }
        float tt = (float)(row + 1);
#pragma unroll
        for (int pp = 0; pp < 8; ++pp) {
            float e = __expf(ldv[2 * pp] * tt);
            float an = ldv[2 * pp + 1] * tt;
            float prr = e * __cosf(an), pri = e * __sinf(an);
            xf[2 * pp]     += prr * pcv[2 * pp]     - pri * pcv[2 * pp + 1];
            xf[2 * pp + 1] += prr * pcv[2 * pp + 1] + pri * pcv[2 * pp];
        }
    }
    // C projection: y[c] = sum_p xr*ct_re - xi*ct_im
    float y[16];
#pragma unroll
    for (int i = 0; i < 16; ++i) y[i] = 0.0f;
    for (int pg = 0; pg < 4; ++pg) {
        int src = wbase | pg;
#pragma unroll
        for (int pp = 0; pp < 8; ++pp) {
            float xr = __shfl(xf[2 * pp], src, 64);
            float xi = __shfl(xf[2 * pp + 1], src, 64);
            const float* cp = &ct[(pg * 8 + pp) * 128 + cg * 16];
            float4 cr0 = *(float4*)&cp[0],  cr1 = *(float4*)&cp[4];
            float4 cr2 = *(float4*)&cp[8],  cr3 = *(float4*)&cp[12];
            float4 ci0 = *(float4*)&cp[64], ci1 = *(float4*)&cp[68];
            float4 ci2 = *(float4*)&cp[72], ci3 = *(float4*)&cp[76];
            y[0]  += xr * cr0.x - xi * ci0.x;  y[1]  += xr * cr0.y - xi * ci0.y;
            y[2]  += xr * cr0.z - xi * ci0.z;  y[3]  += xr * cr0.w - xi * ci0.w;
            y[4]  += xr * cr1.x - xi * ci1.x;  y[5]  += xr * cr1.y - xi * ci1.y;
            y[6]  += xr * cr1.z - xi * ci1.z;  y[7]  += xr * cr1.w - xi * ci1.w;
            y[8]  += xr * cr2.x - xi * ci2.x;  y[9]  += xr * cr2.y - xi * ci2.y;
            y[10] += xr * cr2.z - xi * ci2.z;  y[11] += xr * cr2.w - xi * ci2.w;
            y[12] += xr * cr3.x - xi * ci3.x;  y[13] += xr * cr3.y - xi * ci3.y;
            y[14] += xr * cr3.z - xi * ci3.z;  y[15] += xr * cr3.w - xi * ci3.w;
        }
    }
    // h row, gelu(2y + hn*D)
    float hrow[16], g[16];
#pragma unroll
    for (int j4 = 0; j4 < 4; ++j4)
        *(float4*)&hrow[j4 * 4] = *(const float4*)&h[(r0 + row) * HD + cg * 16 + j4 * 4];
    {
        float dvv[16];
#pragma unroll
        for (int j4 = 0; j4 < 4; ++j4)
            *(float4*)&dvv[j4 * 4] = *(const float4*)&Dv[l * HD + cg * 16 + j4 * 4];
#pragma unroll
        for (int i = 0; i < 16; ++i) {
            int c = cg * 16 + i;
            float hnv = hrow[i] * sa[c] + sb[c];
            float t = 2.0f * y[i] + hnv * dvv[i];
            // gelu_tanh(t) == t * sigmoid(1.595769122f*(t + 0.044715f*t^3))
            float u2 = 1.5957691216057308f * (t + 0.044715f * t * t * t);
            g[i] = t / (1.0f + __expf(-u2));
        }
    }
    // GLU: u = g@w1+b1 ; s = g@w2+b2
    float uacc[16], sacc[16];
#pragma unroll
    for (int j4 = 0; j4 < 4; ++j4) {
        *(float4*)&uacc[j4 * 4] = *(const float4*)&b1[l * HD + cg * 16 + j4 * 4];
        *(float4*)&sacc[j4 * 4] = *(const float4*)&b2[l * HD + cg * 16 + j4 * 4];
    }
    for (int kg = 0; kg < 4; ++kg) {
        int src = wbase | kg;
#pragma unroll
        for (int i = 0; i < 16; ++i) {
            float gk = __shfl(g[i], src, 64);
            const float* p1 = &wl1[(kg * 16 + i) * 64 + cg * 16];
            const float* p2 = &wl2[(kg * 16 + i) * 64 + cg * 16];
            float4 a0 = *(float4*)&p1[0], a1 = *(float4*)&p1[4];
            float4 a2 = *(float4*)&p1[8], a3 = *(float4*)&p1[12];
            float4 c0 = *(float4*)&p2[0], c1 = *(float4*)&p2[4];
            float4 c2 = *(float4*)&p2[8], c3 = *(float4*)&p2[12];
            uacc[0]  += gk * a0.x;  uacc[1]  += gk * a0.y;  uacc[2]  += gk * a0.z;  uacc[3]  += gk * a0.w;
            uacc[4]  += gk * a1.x;  uacc[5]  += gk * a1.y;  uacc[6]  += gk * a1.z;  uacc[7]  += gk * a1.w;
            uacc[8]  += gk * a2.x;  uacc[9]  += gk * a2.y;  uacc[10] += gk * a2.z;  uacc[11] += gk * a2.w;
            uacc[12] += gk * a3.x;  uacc[13] += gk * a3.y;  uacc[14] += gk * a3.z;  uacc[15] += gk * a3.w;
            sacc[0]  += gk * c0.x;  sacc[1]  += gk * c0.y;  sacc[2]  += gk * c0.z;  sacc[3]  += gk * c0.w;
            sacc[4]  += gk * c1.x;  sacc[5]  += gk * c1.y;  sacc[6]  += gk * c1.z;  sacc[7]  += gk * c1.w;
            sacc[8]  += gk * c2.x;  sacc[9]  += gk * c2.y;  sacc[10] += gk * c2.z;  sacc[11] += gk * c2.w;
            sacc[12] += gk * c3.x;  sacc[13] += gk * c3.y;  sacc[14] += gk * c3.z;  sacc[15] += gk * c3.w;
        }
    }
    if (LAST) {
        float dw0[16], dw1[16];
#pragma unroll
        for (int j4 = 0; j4 < 4; ++j4) {
            *(float4*)&dw0[j4 * 4] = *(const float4*)&dec_w[cg * 16 + j4 * 4];
            *(float4*)&dw1[j4 * 4] = *(const float4*)&dec_w[64 + cg * 16 + j4 * 4];
        }
        float o0 = 0.0f, o1 = 0.0f;
#pragma unroll
        for (int i = 0; i < 16; ++i) {
            float sg = 1.0f / (1.0f + __expf(-sacc[i]));
            float ho = hrow[i] + uacc[i] * sg;
            o0 += ho * dw0[i];
            o1 += ho * dw1[i];
        }
        o0 += __shfl_xor(o0, 1, 64); o0 += __shfl_xor(o0, 2, 64);
        o1 += __shfl_xor(o1, 1, 64); o1 += __shfl_xor(o1, 2, 64);
        if (cg == 0)
            *(float2*)&outp[(r0 + row) * 2] = make_float2(o0 + dec_b[0], o1 + dec_b[1]);
    } else {
        float ho[16];
#pragma unroll
        for (int i = 0; i < 16; ++i) {
            float sg = 1.0f / (1.0f + __expf(-sacc[i]));
            ho[i] = hrow[i] + uacc[i] * sg;
        }
#pragma unroll
        for (int j4 = 0; j4 < 4; ++j4)
            *(float4*)&hout[(r0 + row) * HD + cg * 16 + j4 * 4] =
                make_float4(ho[j4 * 4], ho[j4 * 4 + 1], ho[j4 * 4 + 2], ho[j4 * 4 + 3]);
        // next-layer stats
#pragma unroll
        for (int i = 0; i < 16; ++i) {
            float v1 = ho[i], v2 = ho[i] * ho[i];
#pragma unroll
            for (int m = 4; m < 64; m <<= 1) { v1 += __shfl_xor(v1, m, 64); v2 += __shfl_xor(v2, m, 64); }
            if ((lane >> 2) == 0) {
                sp[wid * 128 + cg * 16 + i] = v1;
                sp[wid * 128 + 64 + cg * 16 + i] = v2;
            }
        }
        __syncthreads();
        if (tid < 128) {
            float v = 0.0f;
#pragma unroll
            for (int w = 0; w < 8; ++w) v += sp[w * 128 + tid];
            atomicAdd(&stats_next[tid], v);
        }
    }
}

// ---------------------------------------------------------------- launch
extern "C" void kernel_launch(void* const* d_in, const int* in_sizes, int n_in,
                              void* d_out, int out_size, void* d_ws, size_t ws_size,
                              hipStream_t stream)
{
    (void)in_sizes; (void)n_in; (void)out_size; (void)ws_size;
    const float* x     = (const float*)d_in[0];
    const int*   gidx  = (const int*)d_in[1];
    const float* enc_w = (const float*)d_in[2];
    const float* enc_b = (const float*)d_in[3];
    const float* ctx   = (const float*)d_in[4];
    const float* Lre   = (const float*)d_in[5];
    const float* Lim   = (const float*)d_in[6];
    const float* Bre   = (const float*)d_in[7];
    const float* Bim   = (const float*)d_in[8];
    const float* Cre   = (const float*)d_in[9];
    const float* Cim   = (const float*)d_in[10];
    const float* Dv    = (const float*)d_in[11];
    const float* lstep = (const float*)d_in[12];
    const float* nsc   = (const float*)d_in[13];
    const float* nbi   = (const float*)d_in[14];
    const float* w1    = (const float*)d_in[15];
    const float* b1    = (const float*)d_in[16];
    const float* w2    = (const float*)d_in[17];
    const float* b2    = (const float*)d_in[18];
    const float* dw    = (const float*)d_in[19];
    const float* db    = (const float*)d_in[20];
    float* out = (float*)d_out;

    float* ws = (float*)d_ws;
    float* h      = ws;  ws += (size_t)T_LEN * HD;
    float* xs     = ws;  ws += (size_t)T_LEN * HD;
    float* carry  = ws;  ws += (size_t)NBLK * HD;
    float* pc     = ws;  ws += (size_t)NBLK * HD;
    float* stats  = ws;  ws += NLAY * 128;
    float* Lbar   = ws;  ws += NLAY * PD * 2;
    float* Ldt    = ws;  ws += NLAY * PD * 2;
    float* Bbar_t = ws;  ws += NLAY * HD * HD;
    float* Ct     = ws;  ws += NLAY * PD * 128;
    float* w1t    = ws;  ws += NLAY * HD * HD;
    float* w2t    = ws;  ws += NLAY * HD * HD;
    float* wenc   = ws;  ws += IN_DIM * HD;

    ssm_k0_setup<<<1, 512, 0, stream>>>(Lre, Lim, lstep, Bre, Bim, Cre, Cim, w1, w2,
                                        enc_w, gidx, Lbar, Ldt, Bbar_t, Ct, w1t, w2t,
                                        wenc, stats);
    ssm_k1_encoder<<<1024, 256, 0, stream>>>(x, gidx, wenc, enc_b, ctx, h, stats);
    for (int l = 0; l < NLAY; ++l) {
        ssm_k2_bu_scan<<<NBLK, 512, 0, stream>>>(h, stats, nsc, nbi, Bbar_t, Lbar, xs, carry, l);
        ssm_k3_carry<<<PD, 64, 0, stream>>>(carry, Ldt, pc, l);
        if (l < NLAY - 1) {
            ssm_k4_out<false><<<NBLK, 512, 0, stream>>>(
                h, xs, pc, stats, nsc, nbi, Ldt, Ct, Dv, w1t, b1, w2t, b2,
                h, stats + (l + 1) * 128, dw, db, out, l);
        } else {
            ssm_k4_out<true><<<NBLK, 512, 0, stream>>>(
                h, xs, pc, stats, nsc, nbi, Ldt, Ct, Dv, w1t, b1, w2t, b2,
                h, stats, dw, db, out, l);
        }
    }
}

// Round 3
// 543.594 us; speedup vs baseline: 3.8338x; 1.1218x over previous
//
#include <hip/hip_runtime.h>

#define T_LEN   131072
#define IN_DIM  256
#define HD      64
#define PD      32
#define NLAY    4
#define CHUNK   128
#define NBLK    (T_LEN / CHUNK)   // 1024

// ---------------------------------------------------------------- K0: setup
__global__ __launch_bounds__(512) void ssm_k0_setup(
    const float* __restrict__ Lre, const float* __restrict__ Lim,
    const float* __restrict__ logstep,
    const float* __restrict__ Bre, const float* __restrict__ Bim,
    const float* __restrict__ Cre, const float* __restrict__ Cim,
    const float* __restrict__ w1, const float* __restrict__ w2,
    const float* __restrict__ enc_w, const int* __restrict__ gptr,
    float* __restrict__ Lbar, float* __restrict__ Ldt,
    float* __restrict__ Bbar_t, float* __restrict__ Ct,
    float* __restrict__ w1t, float* __restrict__ w2t,
    float* __restrict__ wenc, float* __restrict__ stats)
{
    __shared__ float fact[NLAY * PD * 2];
    int tid = threadIdx.x;
    if (tid < NLAY * PD) {
        int l = tid >> 5, p = tid & 31;
        float dt = expf(logstep[l * PD + p]);
        float lr = Lre[l * PD + p], li = Lim[l * PD + p];
        float ldr = lr * dt, ldi = li * dt;
        Ldt[tid * 2] = ldr; Ldt[tid * 2 + 1] = ldi;
        float e = expf(ldr);
        float sn, cs; sincosf(ldi, &sn, &cs);
        float lbr = e * cs, lbi = e * sn;
        Lbar[tid * 2] = lbr; Lbar[tid * 2 + 1] = lbi;
        float den = lr * lr + li * li;
        float nr = lbr - 1.0f, ni = lbi;
        fact[tid * 2]     = (nr * lr + ni * li) / den;
        fact[tid * 2 + 1] = (ni * lr - nr * li) / den;
    }
    if (tid < NLAY * 128) stats[tid] = 0.0f;
    __syncthreads();
    // Bbar_t[l][c][2p] ; Ct planes [l][p][re:0..63 | im:64..127]
    for (int idx = tid; idx < NLAY * PD * HD; idx += 512) {
        int lp = idx >> 6; int c = idx & 63;
        int l = lp >> 5, p = lp & 31;
        float fr = fact[lp * 2], fi = fact[lp * 2 + 1];
        float br = Bre[idx], bi = Bim[idx];                    // B is [l][p][h]
        Bbar_t[((size_t)(l * HD + c)) * HD + 2 * p]     = fr * br - fi * bi;
        Bbar_t[((size_t)(l * HD + c)) * HD + 2 * p + 1] = fr * bi + fi * br;
        Ct[((size_t)(l * PD + p)) * 128 + c]      = Cre[(l * HD + c) * PD + p];
        Ct[((size_t)(l * PD + p)) * 128 + 64 + c] = Cim[(l * HD + c) * PD + p];
    }
    for (int idx = tid; idx < NLAY * HD * HD; idx += 512) {
        int l = idx >> 12; int k = (idx >> 6) & 63; int c = idx & 63;
        w1t[idx] = w1[(l * HD + c) * HD + k];
        w2t[idx] = w2[(l * HD + c) * HD + k];
    }
    int g = gptr[0];
    for (int idx = tid; idx < IN_DIM * HD; idx += 512) {
        int k = idx >> 6, ch = idx & 63;
        wenc[idx] = (ch < 56) ? enc_w[((size_t)(g * 56 + ch)) * IN_DIM + k] : 0.0f;
    }
}

// ---------------------------------------------------------------- K1: encoder (unchanged)
__global__ __launch_bounds__(256, 4) void ssm_k1_encoder(
    const float* __restrict__ x, const int* __restrict__ gptr,
    const float* __restrict__ wenc, const float* __restrict__ enc_b,
    const float* __restrict__ ctx_emb,
    float* __restrict__ h, float* __restrict__ stats)
{
    __shared__ __attribute__((aligned(16))) float xl[128 * 68];
    __shared__ __attribute__((aligned(16))) float wl[64 * 68];
    __shared__ float sp[4 * 128];
    int tid = threadIdx.x;
    int row = tid >> 2, cg = tid & 3;
    int lane = tid & 63, wid = tid >> 6;
    int g = gptr[0];
    size_t r0 = (size_t)blockIdx.x * 128;

    float ctxv[8];
#pragma unroll
    for (int j = 0; j < 8; ++j) ctxv[j] = ctx_emb[g * 8 + j];

    float acc[2][16];
#pragma unroll
    for (int rb = 0; rb < 2; ++rb)
#pragma unroll
        for (int i = 0; i < 16; ++i) {
            int ch = cg * 16 + i;
            acc[rb][i] = (ch < 56) ? enc_b[g * 56 + ch] : 0.0f;
        }

    for (int kt = 0; kt < 4; ++kt) {
        __syncthreads();
#pragma unroll
        for (int it = 0; it < 4; ++it) {
            int idx = it * 256 + tid; int kk = idx >> 4, c4 = idx & 15;
            *(float4*)&wl[kk * 68 + c4 * 4] =
                *(const float4*)&wenc[(kt * 64 + kk) * HD + c4 * 4];
        }
#pragma unroll
        for (int it = 0; it < 8; ++it) {
            int idx = it * 256 + tid; int rr = idx >> 4, c4 = idx & 15;
            *(float4*)&xl[rr * 68 + c4 * 4] =
                *(const float4*)&x[(r0 + rr) * IN_DIM + kt * 64 + c4 * 4];
        }
        __syncthreads();
        for (int k = 0; k < 64; ++k) {
            float4 w0 = *(float4*)&wl[k * 68 + cg * 16];
            float4 w1v = *(float4*)&wl[k * 68 + cg * 16 + 4];
            float4 w2v = *(float4*)&wl[k * 68 + cg * 16 + 8];
            float4 w3v = *(float4*)&wl[k * 68 + cg * 16 + 12];
#pragma unroll
            for (int rb = 0; rb < 2; ++rb) {
                float xv = xl[(rb * 64 + row) * 68 + k];
                acc[rb][0]  += xv * w0.x;  acc[rb][1]  += xv * w0.y;
                acc[rb][2]  += xv * w0.z;  acc[rb][3]  += xv * w0.w;
                acc[rb][4]  += xv * w1v.x; acc[rb][5]  += xv * w1v.y;
                acc[rb][6]  += xv * w1v.z; acc[rb][7]  += xv * w1v.w;
                acc[rb][8]  += xv * w2v.x; acc[rb][9]  += xv * w2v.y;
                acc[rb][10] += xv * w2v.z; acc[rb][11] += xv * w2v.w;
                acc[rb][12] += xv * w3v.x; acc[rb][13] += xv * w3v.y;
                acc[rb][14] += xv * w3v.z; acc[rb][15] += xv * w3v.w;
            }
        }
    }
    if (cg == 3) {
#pragma unroll
        for (int rb = 0; rb < 2; ++rb)
#pragma unroll
            for (int i = 8; i < 16; ++i) acc[rb][i] = ctxv[i - 8];
    }
#pragma unroll
    for (int rb = 0; rb < 2; ++rb)
#pragma unroll
        for (int j4 = 0; j4 < 4; ++j4) {
            float4 v = make_float4(acc[rb][j4 * 4], acc[rb][j4 * 4 + 1],
                                   acc[rb][j4 * 4 + 2], acc[rb][j4 * 4 + 3]);
            *(float4*)&h[(r0 + rb * 64 + row) * HD + cg * 16 + j4 * 4] = v;
        }
#pragma unroll
    for (int i = 0; i < 16; ++i) {
        float v1 = acc[0][i] + acc[1][i];
        float v2 = acc[0][i] * acc[0][i] + acc[1][i] * acc[1][i];
#pragma unroll
        for (int m = 4; m < 64; m <<= 1) { v1 += __shfl_xor(v1, m, 64); v2 += __shfl_xor(v2, m, 64); }
        if ((lane >> 2) == 0) {
            sp[wid * 128 + cg * 16 + i] = v1;
            sp[wid * 128 + 64 + cg * 16 + i] = v2;
        }
    }
    __syncthreads();
    if (tid < 128) {
        float v = sp[tid] + sp[128 + tid] + sp[256 + tid] + sp[384 + tid];
        atomicAdd(&stats[tid], v);
    }
}

// ---------------------------------------------------------------- K2: hn -> Bu -> local scan
// 512 threads = 8 waves; wave = (cg = wid&3, rowhalf = wid>>2); lane = row-in-half.
// Weights read with wave-uniform addresses -> s_load (scalar cache), no LDS.
__global__ __launch_bounds__(512, 4) void ssm_k2_bu_scan(
    const float* __restrict__ h, const float* __restrict__ stats,
    const float* __restrict__ nscale, const float* __restrict__ nbias,
    const float* __restrict__ Bbar_t, const float* __restrict__ Lbar,
    float* __restrict__ xs, float* __restrict__ carry, int l)
{
    __shared__ float buf[128 * 66];
    __shared__ float sa[HD], sb[HD];
    int tid = threadIdx.x;
    int lane = tid & 63, wid = tid >> 6;
    int ucg = __builtin_amdgcn_readfirstlane(wid & 3);
    int row = (wid >> 2) * 64 + lane;
    size_t r0 = (size_t)blockIdx.x * CHUNK;

    if (tid < HD) {
        float s1 = stats[l * 128 + tid], s2 = stats[l * 128 + 64 + tid];
        float mu = s1 * (1.0f / T_LEN);
        float var = fmaxf(s2 * (1.0f / T_LEN) - mu * mu, 0.0f);
        float sc = nscale[l * HD + tid] * rsqrtf(var + 1e-5f);
        sa[tid] = sc;
        sb[tid] = nbias[l * HD + tid] - mu * sc;
    }
    __syncthreads();

    // hn for my 16 channels -> LDS [row][c]
#pragma unroll
    for (int j4 = 0; j4 < 4; ++j4) {
        float4 hv = *(const float4*)&h[(r0 + row) * HD + ucg * 16 + j4 * 4];
        int c = ucg * 16 + j4 * 4;
        float2 a = make_float2(hv.x * sa[c]     + sb[c],     hv.y * sa[c + 1] + sb[c + 1]);
        float2 b = make_float2(hv.z * sa[c + 2] + sb[c + 2], hv.w * sa[c + 3] + sb[c + 3]);
        *(float2*)&buf[row * 66 + c]     = a;
        *(float2*)&buf[row * 66 + c + 2] = b;
    }
    __syncthreads();

    // Bu: bacc[2p-slice] = sum_k hn[row][k] * Bbar_t[k][2p-slice]
    float bacc[16];
#pragma unroll
    for (int j = 0; j < 16; ++j) bacc[j] = 0.0f;
    for (int k2 = 0; k2 < 32; ++k2) {
        float2 hk = *(float2*)&buf[row * 66 + 2 * k2];
        const float* b0 = &Bbar_t[(size_t)l * 4096 + (2 * k2) * 64 + ucg * 16];
        const float* b1p = b0 + 64;
        float4 a0 = *(const float4*)&b0[0],  a1 = *(const float4*)&b0[4];
        float4 a2 = *(const float4*)&b0[8],  a3 = *(const float4*)&b0[12];
        float4 c0 = *(const float4*)&b1p[0], c1 = *(const float4*)&b1p[4];
        float4 c2 = *(const float4*)&b1p[8], c3 = *(const float4*)&b1p[12];
        bacc[0]  += hk.x * a0.x + hk.y * c0.x;  bacc[1]  += hk.x * a0.y + hk.y * c0.y;
        bacc[2]  += hk.x * a0.z + hk.y * c0.z;  bacc[3]  += hk.x * a0.w + hk.y * c0.w;
        bacc[4]  += hk.x * a1.x + hk.y * c1.x;  bacc[5]  += hk.x * a1.y + hk.y * c1.y;
        bacc[6]  += hk.x * a1.z + hk.y * c1.z;  bacc[7]  += hk.x * a1.w + hk.y * c1.w;
        bacc[8]  += hk.x * a2.x + hk.y * c2.x;  bacc[9]  += hk.x * a2.y + hk.y * c2.y;
        bacc[10] += hk.x * a2.z + hk.y * c2.z;  bacc[11] += hk.x * a2.w + hk.y * c2.w;
        bacc[12] += hk.x * a3.x + hk.y * c3.x;  bacc[13] += hk.x * a3.y + hk.y * c3.y;
        bacc[14] += hk.x * a3.z + hk.y * c3.z;  bacc[15] += hk.x * a3.w + hk.y * c3.w;
    }
    __syncthreads();   // all hn reads done before overwriting buf with Bu
#pragma unroll
    for (int j2 = 0; j2 < 8; ++j2)
        *(float2*)&buf[row * 66 + ucg * 16 + 2 * j2] =
            make_float2(bacc[2 * j2], bacc[2 * j2 + 1]);
    __syncthreads();

    // in-chunk scan: wave 0, lane = 2p+ri
    if (tid < 64) {
        int p = lane >> 1;
        float Lr = Lbar[(l * PD + p) * 2];
        float Lj = Lbar[(l * PD + p) * 2 + 1];
        float csn = (lane & 1) ? Lj : -Lj;
        float xv = 0.0f;
        for (int t = 0; t < CHUNK; ++t) {
            float b = buf[t * 66 + lane];
            float xo = __shfl_xor(xv, 1, 64);
            xv = Lr * xv + csn * xo + b;
            buf[t * 66 + lane] = xv;
        }
        carry[(size_t)blockIdx.x * 64 + lane] = xv;
    }
    __syncthreads();
#pragma unroll
    for (int j4 = 0; j4 < 4; ++j4) {
        float2 a = *(float2*)&buf[row * 66 + ucg * 16 + 4 * j4];
        float2 b = *(float2*)&buf[row * 66 + ucg * 16 + 4 * j4 + 2];
        *(float4*)&xs[(r0 + row) * HD + ucg * 16 + 4 * j4] = make_float4(a.x, a.y, b.x, b.y);
    }
}

// ---------------------------------------------------------------- K3: cross-chunk carry scan (unchanged)
__global__ __launch_bounds__(64) void ssm_k3_carry(
    const float* __restrict__ carry, const float* __restrict__ Ldt,
    float* __restrict__ pc, int l)
{
    int p = blockIdx.x;
    int lane = threadIdx.x;
    float ldr = Ldt[(l * PD + p) * 2], ldi = Ldt[(l * PD + p) * 2 + 1];
    float er = __expf(ldr * (float)CHUNK);
    float an = ldi * (float)CHUNK;
    float lcr = er * __cosf(an), lci = er * __sinf(an);   // L^CHUNK
    float cr[16], ci[16];
#pragma unroll
    for (int j = 0; j < 16; ++j) {
        cr[j] = carry[(size_t)(lane * 16 + j) * 64 + 2 * p];
        ci[j] = carry[(size_t)(lane * 16 + j) * 64 + 2 * p + 1];
    }
    float ur = 0.0f, ui = 0.0f;
#pragma unroll
    for (int j = 0; j < 16; ++j) {
        float nr = lcr * ur - lci * ui + cr[j];
        float ni = lcr * ui + lci * ur + ci[j];
        ur = nr; ui = ni;
    }
    float mr = lcr, mi = lci;
#pragma unroll
    for (int s = 0; s < 4; ++s) { float t = mr * mr - mi * mi; mi = 2.0f * mr * mi; mr = t; }
#pragma unroll
    for (int d = 1; d < 64; d <<= 1) {
        float tr = __shfl_up(ur, d, 64);
        float ti = __shfl_up(ui, d, 64);
        if (lane >= d) { ur = mr * tr - mi * ti + ur; ui = mr * ti + mi * tr + ui; }
        float t = mr * mr - mi * mi; mi = 2.0f * mr * mi; mr = t;
    }
    float pr = __shfl_up(ur, 1, 64), pi = __shfl_up(ui, 1, 64);
    float xr = (lane == 0) ? 0.0f : pr;
    float xi = (lane == 0) ? 0.0f : pi;
#pragma unroll
    for (int j = 0; j < 16; ++j) {
        pc[(size_t)(lane * 16 + j) * 64 + 2 * p]     = xr;
        pc[(size_t)(lane * 16 + j) * 64 + 2 * p + 1] = xi;
        float nr = lcr * xr - lci * xi + cr[j];
        float ni = lcr * xi + lci * xr + ci[j];
        xr = nr; xi = ni;
    }
}

// ---------------------------------------------------------------- K4: fixup + C-proj + gelu + GLU + residual (+stats / decoder)
// 512 threads = 8 waves; wave = (cg, rowhalf); lane = row. Weights via s_load.
template <bool LAST>
__global__ __launch_bounds__(512, 4) void ssm_k4_out(
    const float* __restrict__ h, const float* __restrict__ xs,
    const float* __restrict__ pc, const float* __restrict__ stats,
    const float* __restrict__ nscale, const float* __restrict__ nbias,
    const float* __restrict__ Ldt, const float* __restrict__ Ct,
    const float* __restrict__ Dv,
    const float* __restrict__ w1t, const float* __restrict__ b1,
    const float* __restrict__ w2t, const float* __restrict__ b2,
    float* __restrict__ hout, float* __restrict__ stats_next,
    const float* __restrict__ dec_w, const float* __restrict__ dec_b,
    float* __restrict__ outp, int l)
{
    __shared__ float buf[128 * 66];
    __shared__ float sa[HD], sb[HD];
    __shared__ float sp1[128], sp2[128];
    int tid = threadIdx.x;
    int lane = tid & 63, wid = tid >> 6;
    int ucg = __builtin_amdgcn_readfirstlane(wid & 3);
    int row = (wid >> 2) * 64 + lane;
    size_t r0 = (size_t)blockIdx.x * CHUNK;

    if (tid < HD) {
        float s1 = stats[l * 128 + tid], s2 = stats[l * 128 + 64 + tid];
        float mu = s1 * (1.0f / T_LEN);
        float var = fmaxf(s2 * (1.0f / T_LEN) - mu * mu, 0.0f);
        float sc = nscale[l * HD + tid] * rsqrtf(var + 1e-5f);
        sa[tid] = sc;
        sb[tid] = nbias[l * HD + tid] - mu * sc;
    }

    // xs slice + carry fixup
    float xf[16];
#pragma unroll
    for (int j4 = 0; j4 < 4; ++j4)
        *(float4*)&xf[j4 * 4] = *(const float4*)&xs[(r0 + row) * HD + ucg * 16 + j4 * 4];
    {
        const float* ldp = &Ldt[(l * PD + ucg * 8) * 2];                // uniform
        const float* pcp = &pc[(size_t)blockIdx.x * 64 + ucg * 16];     // uniform
        float tt = (float)(row + 1);
#pragma unroll
        for (int pp = 0; pp < 8; ++pp) {
            float e = __expf(ldp[2 * pp] * tt);
            float an = ldp[2 * pp + 1] * tt;
            float prr = e * __cosf(an), pri = e * __sinf(an);
            float pr_ = pcp[2 * pp], pi_ = pcp[2 * pp + 1];
            xf[2 * pp]     += prr * pr_ - pri * pi_;
            xf[2 * pp + 1] += prr * pi_ + pri * pr_;
        }
    }
    // exchange xf across channel groups via LDS
#pragma unroll
    for (int j2 = 0; j2 < 8; ++j2)
        *(float2*)&buf[row * 66 + ucg * 16 + 2 * j2] =
            make_float2(xf[2 * j2], xf[2 * j2 + 1]);
    __syncthreads();

    // C projection: y[c] = sum_p xr*Cre - xi*Cim   (weights via s_load)
    float y[16];
#pragma unroll
    for (int i = 0; i < 16; ++i) y[i] = 0.0f;
    for (int p = 0; p < 32; ++p) {
        float2 xv = *(float2*)&buf[row * 66 + 2 * p];
        const float* cp = &Ct[(size_t)l * 4096 + p * 128 + ucg * 16];   // uniform
        float4 r0v = *(const float4*)&cp[0],  r1v = *(const float4*)&cp[4];
        float4 r2v = *(const float4*)&cp[8],  r3v = *(const float4*)&cp[12];
        float4 i0v = *(const float4*)&cp[64], i1v = *(const float4*)&cp[68];
        float4 i2v = *(const float4*)&cp[72], i3v = *(const float4*)&cp[76];
        y[0]  += xv.x * r0v.x - xv.y * i0v.x;  y[1]  += xv.x * r0v.y - xv.y * i0v.y;
        y[2]  += xv.x * r0v.z - xv.y * i0v.z;  y[3]  += xv.x * r0v.w - xv.y * i0v.w;
        y[4]  += xv.x * r1v.x - xv.y * i1v.x;  y[5]  += xv.x * r1v.y - xv.y * i1v.y;
        y[6]  += xv.x * r1v.z - xv.y * i1v.z;  y[7]  += xv.x * r1v.w - xv.y * i1v.w;
        y[8]  += xv.x * r2v.x - xv.y * i2v.x;  y[9]  += xv.x * r2v.y - xv.y * i2v.y;
        y[10] += xv.x * r2v.z - xv.y * i2v.z;  y[11] += xv.x * r2v.w - xv.y * i2v.w;
        y[12] += xv.x * r3v.x - xv.y * i3v.x;  y[13] += xv.x * r3v.y - xv.y * i3v.y;
        y[14] += xv.x * r3v.z - xv.y * i3v.z;  y[15] += xv.x * r3v.w - xv.y * i3v.w;
    }

    // h row, gelu(2y + hn*D)
    float hrow[16], g[16];
#pragma unroll
    for (int j4 = 0; j4 < 4; ++j4)
        *(float4*)&hrow[j4 * 4] = *(const float4*)&h[(r0 + row) * HD + ucg * 16 + j4 * 4];
    {
        const float* dvp = &Dv[l * HD + ucg * 16];                      // uniform
#pragma unroll
        for (int i = 0; i < 16; ++i) {
            int c = ucg * 16 + i;
            float hnv = hrow[i] * sa[c] + sb[c];
            float t = 2.0f * y[i] + hnv * dvp[i];
            float u2 = 1.5957691216057308f * (t + 0.044715f * t * t * t);
            g[i] = t / (1.0f + __expf(-u2));
        }
    }
    __syncthreads();   // all xf reads (C-proj) done before overwriting buf with g
#pragma unroll
    for (int j2 = 0; j2 < 8; ++j2)
        *(float2*)&buf[row * 66 + ucg * 16 + 2 * j2] =
            make_float2(g[2 * j2], g[2 * j2 + 1]);
    __syncthreads();

    // GLU: u = g@w1+b1 ; s = g@w2+b2  (weights via s_load)
    float uacc[16], sacc[16];
    {
        const float* b1p = &b1[l * HD + ucg * 16];
        const float* b2p = &b2[l * HD + ucg * 16];
#pragma unroll
        for (int j4 = 0; j4 < 4; ++j4) {
            *(float4*)&uacc[j4 * 4] = *(const float4*)&b1p[j4 * 4];
            *(float4*)&sacc[j4 * 4] = *(const float4*)&b2p[j4 * 4];
        }
    }
    for (int k2 = 0; k2 < 32; ++k2) {
        float2 gk = *(float2*)&buf[row * 66 + 2 * k2];
        const float* p1 = &w1t[(size_t)l * 4096 + (2 * k2) * 64 + ucg * 16];  // uniform
        const float* p2 = &w2t[(size_t)l * 4096 + (2 * k2) * 64 + ucg * 16];  // uniform
        float4 a00 = *(const float4*)&p1[0],  a01 = *(const float4*)&p1[4];
        float4 a02 = *(const float4*)&p1[8],  a03 = *(const float4*)&p1[12];
        float4 a10 = *(const float4*)&p1[64], a11 = *(const float4*)&p1[68];
        float4 a12 = *(const float4*)&p1[72], a13 = *(const float4*)&p1[76];
        float4 c00 = *(const float4*)&p2[0],  c01 = *(const float4*)&p2[4];
        float4 c02 = *(const float4*)&p2[8],  c03 = *(const float4*)&p2[12];
        float4 c10 = *(const float4*)&p2[64], c11 = *(const float4*)&p2[68];
        float4 c12 = *(const float4*)&p2[72], c13 = *(const float4*)&p2[76];
        uacc[0]  += gk.x * a00.x + gk.y * a10.x;  uacc[1]  += gk.x * a00.y + gk.y * a10.y;
        uacc[2]  += gk.x * a00.z + gk.y * a10.z;  uacc[3]  += gk.x * a00.w + gk.y * a10.w;
        uacc[4]  += gk.x * a01.x + gk.y * a11.x;  uacc[5]  += gk.x * a01.y + gk.y * a11.y;
        uacc[6]  += gk.x * a01.z + gk.y * a11.z;  uacc[7]  += gk.x * a01.w + gk.y * a11.w;
        uacc[8]  += gk.x * a02.x + gk.y * a12.x;  uacc[9]  += gk.x * a02.y + gk.y * a12.y;
        uacc[10] += gk.x * a02.z + gk.y * a12.z;  uacc[11] += gk.x * a02.w + gk.y * a12.w;
        uacc[12] += gk.x * a03.x + gk.y * a13.x;  uacc[13] += gk.x * a03.y + gk.y * a13.y;
        uacc[14] += gk.x * a03.z + gk.y * a13.z;  uacc[15] += gk.x * a03.w + gk.y * a13.w;
        sacc[0]  += gk.x * c00.x + gk.y * c10.x;  sacc[1]  += gk.x * c00.y + gk.y * c10.y;
        sacc[2]  += gk.x * c00.z + gk.y * c10.z;  sacc[3]  += gk.x * c00.w + gk.y * c10.w;
        sacc[4]  += gk.x * c01.x + gk.y * c11.x;  sacc[5]  += gk.x * c01.y + gk.y * c11.y;
        sacc[6]  += gk.x * c01.z + gk.y * c11.z;  sacc[7]  += gk.x * c01.w + gk.y * c11.w;
        sacc[8]  += gk.x * c02.x + gk.y * c12.x;  sacc[9]  += gk.x * c02.y + gk.y * c12.y;
        sacc[10] += gk.x * c02.z + gk.y * c12.z;  sacc[11] += gk.x * c02.w + gk.y * c12.w;
        sacc[12] += gk.x * c03.x + gk.y * c13.x;  sacc[13] += gk.x * c03.y + gk.y * c13.y;
        sacc[14] += gk.x * c03.z + gk.y * c13.z;  sacc[15] += gk.x * c03.w + gk.y * c13.w;
    }

    if (LAST) {
        const float* dwp0 = &dec_w[ucg * 16];        // uniform
        const float* dwp1 = &dec_w[64 + ucg * 16];   // uniform
        float o0 = 0.0f, o1 = 0.0f;
#pragma unroll
        for (int i = 0; i < 16; ++i) {
            float sg = 1.0f / (1.0f + __expf(-sacc[i]));
            float ho = hrow[i] + uacc[i] * sg;
            o0 += ho * dwp0[i];
            o1 += ho * dwp1[i];
        }
        __syncthreads();   // all g reads done before reusing buf for partials
        buf[row * 8 + (wid & 3) * 2]     = o0;
        buf[row * 8 + (wid & 3) * 2 + 1] = o1;
        __syncthreads();
        if (tid < 128) {
            float a0 = buf[tid * 8] + buf[tid * 8 + 2] + buf[tid * 8 + 4] + buf[tid * 8 + 6];
            float a1 = buf[tid * 8 + 1] + buf[tid * 8 + 3] + buf[tid * 8 + 5] + buf[tid * 8 + 7];
            *(float2*)&outp[(r0 + tid) * 2] = make_float2(a0 + dec_b[0], a1 + dec_b[1]);
        }
    } else {
        float ho[16];
#pragma unroll
        for (int i = 0; i < 16; ++i) {
            float sg = 1.0f / (1.0f + __expf(-sacc[i]));
            ho[i] = hrow[i] + uacc[i] * sg;
        }
#pragma unroll
        for (int j4 = 0; j4 < 4; ++j4)
            *(float4*)&hout[(r0 + row) * HD + ucg * 16 + j4 * 4] =
                make_float4(ho[j4 * 4], ho[j4 * 4 + 1], ho[j4 * 4 + 2], ho[j4 * 4 + 3]);
        // next-layer stats: lanes of a wave are 64 distinct rows -> full-wave reduce
#pragma unroll
        for (int i = 0; i < 16; ++i) {
            float v1 = ho[i], v2 = ho[i] * ho[i];
#pragma unroll
            for (int m = 1; m < 64; m <<= 1) { v1 += __shfl_xor(v1, m, 64); v2 += __shfl_xor(v2, m, 64); }
            if (lane == 0) { sp1[wid * 16 + i] = v1; sp2[wid * 16 + i] = v2; }
        }
        __syncthreads();
        if (tid < 64) {
            atomicAdd(&stats_next[tid],      sp1[tid] + sp1[64 + tid]);
            atomicAdd(&stats_next[64 + tid], sp2[tid] + sp2[64 + tid]);
        }
    }
}

// ---------------------------------------------------------------- launch
extern "C" void kernel_launch(void* const* d_in, const int* in_sizes, int n_in,
                              void* d_out, int out_size, void* d_ws, size_t ws_size,
                              hipStream_t stream)
{
    (void)in_sizes; (void)n_in; (void)out_size; (void)ws_size;
    const float* x     = (const float*)d_in[0];
    const int*   gidx  = (const int*)d_in[1];
    const float* enc_w = (const float*)d_in[2];
    const float* enc_b = (const float*)d_in[3];
    const float* ctx   = (const float*)d_in[4];
    const float* Lre   = (const float*)d_in[5];
    const float* Lim   = (const float*)d_in[6];
    const float* Bre   = (const float*)d_in[7];
    const float* Bim   = (const float*)d_in[8];
    const float* Cre   = (const float*)d_in[9];
    const float* Cim   = (const float*)d_in[10];
    const float* Dv    = (const float*)d_in[11];
    const float* lstep = (const float*)d_in[12];
    const float* nsc   = (const float*)d_in[13];
    const float* nbi   = (const float*)d_in[14];
    const float* w1    = (const float*)d_in[15];
    const float* b1    = (const float*)d_in[16];
    const float* w2    = (const float*)d_in[17];
    const float* b2    = (const float*)d_in[18];
    const float* dw    = (const float*)d_in[19];
    const float* db    = (const float*)d_in[20];
    float* out = (float*)d_out;

    float* ws = (float*)d_ws;
    float* h      = ws;  ws += (size_t)T_LEN * HD;
    float* xs     = ws;  ws += (size_t)T_LEN * HD;
    float* carry  = ws;  ws += (size_t)NBLK * HD;
    float* pc     = ws;  ws += (size_t)NBLK * HD;
    float* stats  = ws;  ws += NLAY * 128;
    float* Lbar   = ws;  ws += NLAY * PD * 2;
    float* Ldt    = ws;  ws += NLAY * PD * 2;
    float* Bbar_t = ws;  ws += NLAY * HD * HD;
    float* Ct     = ws;  ws += NLAY * PD * 128;
    float* w1t    = ws;  ws += NLAY * HD * HD;
    float* w2t    = ws;  ws += NLAY * HD * HD;
    float* wenc   = ws;  ws += IN_DIM * HD;

    ssm_k0_setup<<<1, 512, 0, stream>>>(Lre, Lim, lstep, Bre, Bim, Cre, Cim, w1, w2,
                                        enc_w, gidx, Lbar, Ldt, Bbar_t, Ct, w1t, w2t,
                                        wenc, stats);
    ssm_k1_encoder<<<1024, 256, 0, stream>>>(x, gidx, wenc, enc_b, ctx, h, stats);
    for (int l = 0; l < NLAY; ++l) {
        ssm_k2_bu_scan<<<NBLK, 512, 0, stream>>>(h, stats, nsc, nbi, Bbar_t, Lbar, xs, carry, l);
        ssm_k3_carry<<<PD, 64, 0, stream>>>(carry, Ldt, pc, l);
        if (l < NLAY - 1) {
            ssm_k4_out<false><<<NBLK, 512, 0, stream>>>(
                h, xs, pc, stats, nsc, nbi, Ldt, Ct, Dv, w1t, b1, w2t, b2,
                h, stats + (l + 1) * 128, dw, db, out, l);
        } else {
            ssm_k4_out<true><<<NBLK, 512, 0, stream>>>(
                h, xs, pc, stats, nsc, nbi, Ldt, Ct, Dv, w1t, b1, w2t, b2,
                h, stats, dw, db, out, l);
        }
    }
}